// Round 8
// baseline (490.793 us; speedup 1.0000x reference)
//
#include <hip/hip_runtime.h>

#define NN 100000
#define NE 1000000
#define NG 2048
#define NBLK 98        // ceil(NN/1024)
#define CSRCAP 2600000 // sum(max(16,ceil(d/8)*8)) <= E + 15*N = 2.5M

__device__ __forceinline__ float rl(float v, int k) {
    return __int_as_float(__builtin_amdgcn_readlane(__float_as_int(v), k));
}
__device__ __forceinline__ int rfl(int v) { return __builtin_amdgcn_readfirstlane(v); }

// padded degree: at least 16 (two unconditional chunks), multiple of 8
#define PDEG(c) (max(16, ((c) + 7) & ~7))

// ---------------- graph preprocessing ----------------

// degree count; atomic return value = this edge's slot within its dst list (ticket).
// also per-graph node count.
__global__ void k_cnt(const int* __restrict__ dst, int* __restrict__ cnt,
                      int* __restrict__ ticket,
                      const int* __restrict__ batch, int* __restrict__ pcnt) {
    int i = blockIdx.x * blockDim.x + threadIdx.x;
    if (i < NE) ticket[i] = atomicAdd(&cnt[dst[i]], 1);
    if (i < NN) atomicAdd(&pcnt[batch[i]], 1);
}

// per-block (1024 nodes) padded-degree sums; fused: dinv + px = x*dinv + zero row NN.
__global__ void k_scan1(const int* __restrict__ cnt, int* __restrict__ bsum,
                        const float* __restrict__ x, float* __restrict__ dinv,
                        float* __restrict__ px, float* __restrict__ p1,
                        float* __restrict__ p2) {
    int t = threadIdx.x;
    int base = blockIdx.x * 1024 + t * 4;
    int4 v = {0, 0, 0, 0};
    if (base < NN) v = *(const int4*)(cnt + base);  // NN % 4 == 0
    int s = PDEG(v.x) + PDEG(v.y) + PDEG(v.z) + PDEG(v.w);
    #pragma unroll
    for (int off = 32; off; off >>= 1) s += __shfl_down(s, off, 64);
    __shared__ int ws[4];
    if ((t & 63) == 0) ws[t >> 6] = s;
    __syncthreads();
    if (t == 0) bsum[blockIdx.x] = ws[0] + ws[1] + ws[2] + ws[3];

    if (base < NN) {
        int c[4] = {v.x, v.y, v.z, v.w};
        #pragma unroll
        for (int j2 = 0; j2 < 4; ++j2) {
            int nd = base + j2;
            float dv = rsqrtf((float)(c[j2] + 1));   // +1: self-loop
            dinv[nd] = dv;
            #pragma unroll
            for (int j = 0; j < 9; ++j) px[nd * 9 + j] = x[nd * 9 + j] * dv;
        }
    } else if (base == NN) {   // zero dummy row NN of px / p1 / p2
        #pragma unroll
        for (int j = 0; j < 9; ++j) px[NN * 9 + j] = 0.f;
        for (int j = 0; j < 64; ++j) {
            p1[(size_t)NN * 64 + j] = 0.f;
            p2[(size_t)NN * 64 + j] = 0.f;
        }
    }
}

__global__ void k_scan2(const int* __restrict__ bsum, int* __restrict__ boff, int nb) {
    __shared__ int buf[128];
    int t = threadIdx.x;
    int v = (t < nb) ? bsum[t] : 0;
    buf[t] = v;
    __syncthreads();
    for (int off = 1; off < 128; off <<= 1) {
        int u = (t >= off) ? buf[t - off] : 0;
        __syncthreads();
        buf[t] += u;
        __syncthreads();
    }
    if (t < nb) boff[t] = buf[t] - v;  // exclusive
}

__global__ void k_scan3(const int* __restrict__ cnt, const int* __restrict__ boff,
                        int* __restrict__ prp, int n) {
    int t = threadIdx.x;
    int base = blockIdx.x * 1024 + t * 4;
    int4 v = {0, 0, 0, 0};
    if (base < n) v = *(const int4*)(cnt + base);
    int p0 = PDEG(v.x), p1 = PDEG(v.y), p2 = PDEG(v.z), p3 = PDEG(v.w);
    int s = p0 + p1 + p2 + p3;
    int lane = t & 63;
    int ps = s;
    #pragma unroll
    for (int off = 1; off < 64; off <<= 1) {
        int u = __shfl_up(ps, off, 64);
        if (lane >= off) ps += u;
    }
    __shared__ int ws[4];
    if (lane == 63) ws[t >> 6] = ps;
    __syncthreads();
    int w = t >> 6;
    int woff = 0;
    for (int i = 0; i < 4; ++i) woff += (i < w) ? ws[i] : 0;
    int excl = boff[blockIdx.x] + woff + ps - s;
    if (base < n) {
        prp[base] = excl;          excl += p0;
        prp[base + 1] = excl;      excl += p1;
        prp[base + 2] = excl;      excl += p2;
        prp[base + 3] = excl;      excl += p3;
        if (base + 4 == n) prp[n] = excl;   // total padded slots
    }
}

// init padded CSR to the dummy zero-row id
__global__ void k_padinit(int* __restrict__ csr) {
    int i = blockIdx.x * blockDim.x + threadIdx.x;
    if (i * 4 < CSRCAP) {
        int4 v = {NN, NN, NN, NN};
        *(int4*)(csr + i * 4) = v;
    }
}

// atomic-free CSR fill using tickets
__global__ void k_fill(const int* __restrict__ src, const int* __restrict__ dst,
                       const int* __restrict__ prp, const int* __restrict__ ticket,
                       int* __restrict__ csr, int E) {
    int i = blockIdx.x * blockDim.x + threadIdx.x;
    if (i < E) csr[prp[dst[i]] + ticket[i]] = src[i];
}

// ---------------- fused GCN layer ----------------
// relu(Agg(a.W)+b) == relu((dinv .* (p_self + sum_src p_src)) . W + b),  p = a .* dinv.
// pdeg >= 16 for ALL nodes -> phase B is one branchless block of 128 independent
// gather loads (8 nodes x 2 chunks); tail loop only for pdeg>16 (~3% of nodes).
// Wave = 8 nodes, lane = output feature; matvec via readlane broadcast.

template <int KD, int POOL>
__global__ __launch_bounds__(256, 6)
void k_layer(const float* __restrict__ pin, const float* __restrict__ W,
             const float* __restrict__ bias, const float* __restrict__ dinv,
             const int* __restrict__ csr, const int* __restrict__ prp,
             const int* __restrict__ batch,
             float* __restrict__ pout, float* __restrict__ psum,
             float* __restrict__ pmax) {
    __shared__ float Ws[KD * 64];
    int tid = threadIdx.x;
    for (int i = tid; i < KD * 64; i += 256) Ws[i] = W[i];
    __syncthreads();
    int f = tid & 63;
    int wv = tid >> 6;
    int n0 = (blockIdx.x * 4 + wv) * 8;           // NN == 3125*32: no tail
    int fi = (KD < 64) ? ((f < KD) ? f : (KD - 1)) : f;

#define CHUNK(A0, A1, E0) { \
    int s0 = csr[(E0) + 0], s1 = csr[(E0) + 1], s2 = csr[(E0) + 2], s3 = csr[(E0) + 3]; \
    int s4 = csr[(E0) + 4], s5 = csr[(E0) + 5], s6 = csr[(E0) + 6], s7 = csr[(E0) + 7]; \
    A0 += pin[(size_t)s0 * KD + fi]; A1 += pin[(size_t)s1 * KD + fi]; \
    A0 += pin[(size_t)s2 * KD + fi]; A1 += pin[(size_t)s3 * KD + fi]; \
    A0 += pin[(size_t)s4 * KD + fi]; A1 += pin[(size_t)s5 * KD + fi]; \
    A0 += pin[(size_t)s6 * KD + fi]; A1 += pin[(size_t)s7 * KD + fi]; \
}

    // phase A: bounds + self rows (8 nodes)
#define BOUNDS(J) \
    int pb##J = rfl(prp[n0 + J]); int pe##J = rfl(prp[n0 + J + 1]); \
    float a##J##0 = pin[(size_t)(n0 + J) * KD + fi]; float a##J##1 = 0.f;
    BOUNDS(0) BOUNDS(1) BOUNDS(2) BOUNDS(3)
    BOUNDS(4) BOUNDS(5) BOUNDS(6) BOUNDS(7)
#undef BOUNDS

    // phase B: two unconditional chunks per node, interleaved across nodes
#define CH0(J) CHUNK(a##J##0, a##J##1, pb##J)
    CH0(0) CH0(1) CH0(2) CH0(3) CH0(4) CH0(5) CH0(6) CH0(7)
#undef CH0
#define CH1(J) CHUNK(a##J##0, a##J##1, pb##J + 8)
    CH1(0) CH1(1) CH1(2) CH1(3) CH1(4) CH1(5) CH1(6) CH1(7)
#undef CH1

    // tail (pdeg > 16, rare, wave-uniform) + finalize q
    float q0, q1, q2, q3, q4, q5, q6, q7;
#define TAILQ(Q, J) { \
    for (int e = pb##J + 16; e < pe##J; e += 8) CHUNK(a##J##0, a##J##1, e) \
    Q = (a##J##0 + a##J##1) * dinv[n0 + J]; \
}
    TAILQ(q0, 0) TAILQ(q1, 1) TAILQ(q2, 2) TAILQ(q3, 3)
    TAILQ(q4, 4) TAILQ(q5, 5) TAILQ(q6, 6) TAILQ(q7, 7)
#undef TAILQ
#undef CHUNK

    float bv = bias[f];
    float o0 = bv, o1 = bv, o2 = bv, o3 = bv, o4 = bv, o5 = bv, o6 = bv, o7 = bv;
    #pragma unroll
    for (int k = 0; k < KD; ++k) {
        float wsv = Ws[k * 64 + f];               // lane=f -> bank f%32: conflict-free
        o0 = fmaf(rl(q0, k), wsv, o0);
        o1 = fmaf(rl(q1, k), wsv, o1);
        o2 = fmaf(rl(q2, k), wsv, o2);
        o3 = fmaf(rl(q3, k), wsv, o3);
        o4 = fmaf(rl(q4, k), wsv, o4);
        o5 = fmaf(rl(q5, k), wsv, o5);
        o6 = fmaf(rl(q6, k), wsv, o6);
        o7 = fmaf(rl(q7, k), wsv, o7);
    }

    if (POOL == 0) {
#define STORE(O, J) pout[(size_t)(n0 + (J)) * 64 + f] = fmaxf(O, 0.f) * dinv[n0 + (J)];
        STORE(o0, 0) STORE(o1, 1) STORE(o2, 2) STORE(o3, 3)
        STORE(o4, 4) STORE(o5, 5) STORE(o6, 6) STORE(o7, 7)
#undef STORE
    } else {
        int g = batch[n0];
        float sum = 0.f, mx = 0.f;
#define ACCP(O, J) { \
    float r = fmaxf(O, 0.f); \
    int gj = batch[n0 + (J)]; \
    if (gj != g) { \
        atomicAdd(&psum[g * 64 + f], sum); \
        atomicMax((int*)&pmax[g * 64 + f], __float_as_int(mx)); \
        g = gj; sum = 0.f; mx = 0.f; \
    } \
    sum += r; mx = fmaxf(mx, r); \
}
        ACCP(o0, 0) ACCP(o1, 1) ACCP(o2, 2) ACCP(o3, 3)
        ACCP(o4, 4) ACCP(o5, 5) ACCP(o6, 6) ACCP(o7, 7)
#undef ACCP
        atomicAdd(&psum[g * 64 + f], sum);
        atomicMax((int*)&pmax[g * 64 + f], __float_as_int(mx));  // relu => mx >= 0
    }
}

// ---------------- predictor MLP ----------------

__global__ void k_pred(const float* __restrict__ psum, const float* __restrict__ pmax,
                       const int* __restrict__ pcnt,
                       const float* __restrict__ Wp1, const float* __restrict__ bp1,
                       const float* __restrict__ Wp2, const float* __restrict__ bp2,
                       float* __restrict__ out, int G) {
    __shared__ float gs[4][128];
    int tid = threadIdx.x;
    int li = tid >> 6;
    int lane = tid & 63;
    int gi = blockIdx.x * 4 + li;
    if (gi < G) {
        float c = fmaxf((float)pcnt[gi], 1.0f);
        gs[li][lane] = psum[gi * 64 + lane] / c;
        gs[li][64 + lane] = pmax[gi * 64 + lane];
    }
    __syncthreads();
    if (gi >= G) return;
    float acc = bp1[lane];
    #pragma unroll
    for (int k = 0; k < 128; ++k) acc += gs[li][k] * Wp1[k * 64 + lane];
    acc = fmaxf(acc, 0.f);
    float r = acc * Wp2[lane];
    #pragma unroll
    for (int off = 32; off; off >>= 1) r += __shfl_down(r, off, 64);
    if (lane == 0) out[gi] = r + bp2[0];
}

// ---------------- launch ----------------

extern "C" void kernel_launch(void* const* d_in, const int* in_sizes, int n_in,
                              void* d_out, int out_size, void* d_ws, size_t ws_size,
                              hipStream_t stream) {
    const float* x    = (const float*)d_in[0];
    const int*   esrc = (const int*)d_in[1];
    const int*   edst = (const int*)d_in[2];
    const int*   batch= (const int*)d_in[3];
    const float* W1 = (const float*)d_in[4];  const float* b1 = (const float*)d_in[5];
    const float* W2 = (const float*)d_in[6];  const float* b2 = (const float*)d_in[7];
    const float* W3 = (const float*)d_in[8];  const float* b3 = (const float*)d_in[9];
    const float* Wp1= (const float*)d_in[10]; const float* bp1= (const float*)d_in[11];
    const float* Wp2= (const float*)d_in[12]; const float* bp2= (const float*)d_in[13];
    float* out = (float*)d_out;

    char* ws = (char*)d_ws;
    // zero-init region (contiguous): [cnt][psum][pmax][pcnt]
    int*   cnt     = (int*)  (ws + 0);          // N ints
    float* psum    = (float*)(ws + 400000);     // G*64 floats -> 924288
    float* pmax    = (float*)(ws + 924288);     // G*64 floats -> 1448576
    int*   pcnt    = (int*)  (ws + 1448576);    // G ints -> 1456768
    const size_t ZBYTES = 1456768;
    float* dinv    = (float*)(ws + 1456768);    // N floats -> 1856768
    int*   prp     = (int*)  (ws + 1856768);    // N+1 ints -> 2256896 (pad to 2257408)
    int*   bsum    = (int*)  (ws + 2257408);    // 128 ints -> 2257920
    int*   boff    = (int*)  (ws + 2257920);    // 128 ints -> 2258432
    int*   csr_pad = (int*)  (ws + 2258432);    // CSRCAP ints -> 12658432
    float* p1      = (float*)(ws + 12658432);   // (N+1)*64 floats -> 38258688
    float* p2      = (float*)(ws + 38258688);   // (N+1)*64 floats -> 63858944
    int*   ticket  = (int*)  (ws + 12658432);   // E ints, overlays p1 (dead before layer1)
    float* px      = (float*)(ws + 38258688);   // (N+1)*9 floats, overlays p2 (dead after layer1)

    hipMemsetAsync(ws, 0, ZBYTES, stream);

    k_cnt    <<<(NE + 255) / 256, 256, 0, stream>>>(edst, cnt, ticket, batch, pcnt);
    k_scan1  <<<NBLK, 256, 0, stream>>>(cnt, bsum, x, dinv, px, p1, p2);
    k_scan2  <<<1, 128, 0, stream>>>(bsum, boff, NBLK);
    k_scan3  <<<NBLK, 256, 0, stream>>>(cnt, boff, prp, NN);
    k_padinit<<<(CSRCAP / 4 + 255) / 256, 256, 0, stream>>>(csr_pad);
    k_fill   <<<(NE + 255) / 256, 256, 0, stream>>>(esrc, edst, prp, ticket, csr_pad, NE);

    int nbl = NN / 32;  // 3125, exact
    k_layer<9, 0><<<nbl, 256, 0, stream>>>(px, W1, b1, dinv, csr_pad, prp, batch, p1, psum, pmax);
    k_layer<64, 0><<<nbl, 256, 0, stream>>>(p1, W2, b2, dinv, csr_pad, prp, batch, p2, psum, pmax);
    k_layer<64, 1><<<nbl, 256, 0, stream>>>(p2, W3, b3, dinv, csr_pad, prp, batch, p1, psum, pmax);

    k_pred <<<(NG + 3) / 4, 256, 0, stream>>>(psum, pmax, pcnt, Wp1, bp1, Wp2, bp2, out, NG);
}

// Round 9
// 244.742 us; speedup vs baseline: 2.0054x; 2.0054x over previous
//
#include <hip/hip_runtime.h>

#define NN 100000
#define NE 1000000
#define NG 2048
#define NBLK 98        // ceil(NN/1024)
#define CSRCAP 2600000 // sum(max(16,ceil(d/8)*8)) <= E + 15*N = 2.5M

__device__ __forceinline__ float rl(float v, int k) {
    return __int_as_float(__builtin_amdgcn_readlane(__float_as_int(v), k));
}
__device__ __forceinline__ int rli(int v, int k) {
    return __builtin_amdgcn_readlane(v, k);
}

// padded degree: at least 16 (two unconditional chunks even for deg 0), multiple of 8
#define PDEG(c) (max(16, ((c) + 7) & ~7))

// ---------------- graph preprocessing ----------------

// degree count; atomic return value = this edge's slot within its dst list (ticket).
// also per-graph node count.
__global__ void k_cnt(const int* __restrict__ dst, int* __restrict__ cnt,
                      int* __restrict__ ticket,
                      const int* __restrict__ batch, int* __restrict__ pcnt) {
    int i = blockIdx.x * blockDim.x + threadIdx.x;
    if (i < NE) ticket[i] = atomicAdd(&cnt[dst[i]], 1);
    if (i < NN) atomicAdd(&pcnt[batch[i]], 1);
}

// per-block (1024 nodes) padded-degree sums; fused: dinv + px = x*dinv + zero row NN.
__global__ void k_scan1(const int* __restrict__ cnt, int* __restrict__ bsum,
                        const float* __restrict__ x, float* __restrict__ dinv,
                        float* __restrict__ px, float* __restrict__ p1,
                        float* __restrict__ p2) {
    int t = threadIdx.x;
    int base = blockIdx.x * 1024 + t * 4;
    int4 v = {0, 0, 0, 0};
    if (base < NN) v = *(const int4*)(cnt + base);  // NN % 4 == 0
    int s = PDEG(v.x) + PDEG(v.y) + PDEG(v.z) + PDEG(v.w);
    #pragma unroll
    for (int off = 32; off; off >>= 1) s += __shfl_down(s, off, 64);
    __shared__ int ws[4];
    if ((t & 63) == 0) ws[t >> 6] = s;
    __syncthreads();
    if (t == 0) bsum[blockIdx.x] = ws[0] + ws[1] + ws[2] + ws[3];

    if (base < NN) {
        int c[4] = {v.x, v.y, v.z, v.w};
        #pragma unroll
        for (int j2 = 0; j2 < 4; ++j2) {
            int nd = base + j2;
            float dv = rsqrtf((float)(c[j2] + 1));   // +1: self-loop
            dinv[nd] = dv;
            #pragma unroll
            for (int j = 0; j < 9; ++j) px[nd * 9 + j] = x[nd * 9 + j] * dv;
        }
    } else if (base == NN) {   // zero dummy row NN of px / p1 / p2
        #pragma unroll
        for (int j = 0; j < 9; ++j) px[NN * 9 + j] = 0.f;
        for (int j = 0; j < 64; ++j) {
            p1[(size_t)NN * 64 + j] = 0.f;
            p2[(size_t)NN * 64 + j] = 0.f;
        }
    }
}

__global__ void k_scan2(const int* __restrict__ bsum, int* __restrict__ boff, int nb) {
    __shared__ int buf[128];
    int t = threadIdx.x;
    int v = (t < nb) ? bsum[t] : 0;
    buf[t] = v;
    __syncthreads();
    for (int off = 1; off < 128; off <<= 1) {
        int u = (t >= off) ? buf[t - off] : 0;
        __syncthreads();
        buf[t] += u;
        __syncthreads();
    }
    if (t < nb) boff[t] = buf[t] - v;  // exclusive
}

__global__ void k_scan3(const int* __restrict__ cnt, const int* __restrict__ boff,
                        int* __restrict__ prp, int n) {
    int t = threadIdx.x;
    int base = blockIdx.x * 1024 + t * 4;
    int4 v = {0, 0, 0, 0};
    if (base < n) v = *(const int4*)(cnt + base);
    int p0 = PDEG(v.x), p1 = PDEG(v.y), p2 = PDEG(v.z), p3 = PDEG(v.w);
    int s = p0 + p1 + p2 + p3;
    int lane = t & 63;
    int ps = s;
    #pragma unroll
    for (int off = 1; off < 64; off <<= 1) {
        int u = __shfl_up(ps, off, 64);
        if (lane >= off) ps += u;
    }
    __shared__ int ws[4];
    if (lane == 63) ws[t >> 6] = ps;
    __syncthreads();
    int w = t >> 6;
    int woff = 0;
    for (int i = 0; i < 4; ++i) woff += (i < w) ? ws[i] : 0;
    int excl = boff[blockIdx.x] + woff + ps - s;
    if (base < n) {
        prp[base] = excl;          excl += p0;
        prp[base + 1] = excl;      excl += p1;
        prp[base + 2] = excl;      excl += p2;
        prp[base + 3] = excl;      excl += p3;
        if (base + 4 == n) prp[n] = excl;   // total padded slots
    }
}

// init padded CSR to the dummy zero-row id
__global__ void k_padinit(int* __restrict__ csr) {
    int i = blockIdx.x * blockDim.x + threadIdx.x;
    if (i * 4 < CSRCAP) {
        int4 v = {NN, NN, NN, NN};
        *(int4*)(csr + i * 4) = v;
    }
}

// atomic-free CSR fill using tickets
__global__ void k_fill(const int* __restrict__ src, const int* __restrict__ dst,
                       const int* __restrict__ prp, const int* __restrict__ ticket,
                       int* __restrict__ csr, int E) {
    int i = blockIdx.x * blockDim.x + threadIdx.x;
    if (i < E) csr[prp[dst[i]] + ticket[i]] = src[i];
}

// ---------------- fused GCN layer ----------------
// relu(Agg(a.W)+b) == relu((dinv .* (p_self + sum_src p_src)) . W + b),  p = a .* dinv.
// pdeg >= 16 for ALL nodes (deg 0 included) -> per PAIR of nodes one branchless
// block of 34 independent loads (2 selfs + 4 chunks); rare uniform tails after.
// Pairing doubles round-7's in-flight window without round-8's 8x burst
// (which collapsed L2 hit rate: FETCH 125->247 MB).
// Wave = 8 nodes, lane = output feature; matvec via readlane broadcast.

template <int KD, int POOL>
__global__ __launch_bounds__(256, 6)
void k_layer(const float* __restrict__ pin, const float* __restrict__ W,
             const float* __restrict__ bias, const float* __restrict__ dinv,
             const int* __restrict__ csr, const int* __restrict__ prp,
             const int* __restrict__ batch,
             float* __restrict__ pout, float* __restrict__ psum,
             float* __restrict__ pmax) {
    __shared__ float Ws[KD * 64];
    int tid = threadIdx.x;
    for (int i = tid; i < KD * 64; i += 256) Ws[i] = W[i];
    __syncthreads();
    int f = tid & 63;
    int wv = tid >> 6;
    int n0 = (blockIdx.x * 4 + wv) * 8;           // NN == 3125*32: no tail
    int fi = (KD < 64) ? ((f < KD) ? f : (KD - 1)) : f;

    // one coalesced load: prp[n0..n0+8] into lanes 0..8, broadcast via readlane
    int myrp = prp[n0 + min(f, 8)];

#define CHUNK(A0, A1, E0) { \
    int s0 = csr[(E0) + 0], s1 = csr[(E0) + 1], s2 = csr[(E0) + 2], s3 = csr[(E0) + 3]; \
    int s4 = csr[(E0) + 4], s5 = csr[(E0) + 5], s6 = csr[(E0) + 6], s7 = csr[(E0) + 7]; \
    float v0 = pin[(size_t)s0 * KD + fi], v1 = pin[(size_t)s1 * KD + fi]; \
    float v2 = pin[(size_t)s2 * KD + fi], v3 = pin[(size_t)s3 * KD + fi]; \
    float v4 = pin[(size_t)s4 * KD + fi], v5 = pin[(size_t)s5 * KD + fi]; \
    float v6 = pin[(size_t)s6 * KD + fi], v7 = pin[(size_t)s7 * KD + fi]; \
    A0 += (v0 + v2) + (v4 + v6); \
    A1 += (v1 + v3) + (v5 + v7); \
}

    float q0, q1, q2, q3, q4, q5, q6, q7;
#define PAIR(JA, JB, QA, QB) { \
    int ndA = n0 + (JA), ndB = n0 + (JB); \
    int pbA = rli(myrp, JA), peA = rli(myrp, (JA) + 1); \
    int pbB = rli(myrp, JB), peB = rli(myrp, (JB) + 1); \
    float aA0 = pin[(size_t)ndA * KD + fi], aA1 = 0.f; \
    float aB0 = pin[(size_t)ndB * KD + fi], aB1 = 0.f; \
    CHUNK(aA0, aA1, pbA) \
    CHUNK(aB0, aB1, pbB) \
    CHUNK(aA0, aA1, pbA + 8) \
    CHUNK(aB0, aB1, pbB + 8) \
    for (int e = pbA + 16; e < peA; e += 8) CHUNK(aA0, aA1, e) \
    for (int e = pbB + 16; e < peB; e += 8) CHUNK(aB0, aB1, e) \
    QA = (aA0 + aA1) * dinv[ndA]; \
    QB = (aB0 + aB1) * dinv[ndB]; \
}
    PAIR(0, 1, q0, q1)
    PAIR(2, 3, q2, q3)
    PAIR(4, 5, q4, q5)
    PAIR(6, 7, q6, q7)
#undef PAIR
#undef CHUNK

    float bv = bias[f];
    float o0 = bv, o1 = bv, o2 = bv, o3 = bv, o4 = bv, o5 = bv, o6 = bv, o7 = bv;
    #pragma unroll
    for (int k = 0; k < KD; ++k) {
        float wsv = Ws[k * 64 + f];               // lane=f -> bank f%32: conflict-free
        o0 = fmaf(rl(q0, k), wsv, o0);
        o1 = fmaf(rl(q1, k), wsv, o1);
        o2 = fmaf(rl(q2, k), wsv, o2);
        o3 = fmaf(rl(q3, k), wsv, o3);
        o4 = fmaf(rl(q4, k), wsv, o4);
        o5 = fmaf(rl(q5, k), wsv, o5);
        o6 = fmaf(rl(q6, k), wsv, o6);
        o7 = fmaf(rl(q7, k), wsv, o7);
    }

    if (POOL == 0) {
#define STORE(O, J) pout[(size_t)(n0 + (J)) * 64 + f] = fmaxf(O, 0.f) * dinv[n0 + (J)];
        STORE(o0, 0) STORE(o1, 1) STORE(o2, 2) STORE(o3, 3)
        STORE(o4, 4) STORE(o5, 5) STORE(o6, 6) STORE(o7, 7)
#undef STORE
    } else {
        int g = batch[n0];
        float sum = 0.f, mx = 0.f;
#define ACCP(O, J) { \
    float r = fmaxf(O, 0.f); \
    int gj = batch[n0 + (J)]; \
    if (gj != g) { \
        atomicAdd(&psum[g * 64 + f], sum); \
        atomicMax((int*)&pmax[g * 64 + f], __float_as_int(mx)); \
        g = gj; sum = 0.f; mx = 0.f; \
    } \
    sum += r; mx = fmaxf(mx, r); \
}
        ACCP(o0, 0) ACCP(o1, 1) ACCP(o2, 2) ACCP(o3, 3)
        ACCP(o4, 4) ACCP(o5, 5) ACCP(o6, 6) ACCP(o7, 7)
#undef ACCP
        atomicAdd(&psum[g * 64 + f], sum);
        atomicMax((int*)&pmax[g * 64 + f], __float_as_int(mx));  // relu => mx >= 0
    }
}

// ---------------- predictor MLP ----------------

__global__ void k_pred(const float* __restrict__ psum, const float* __restrict__ pmax,
                       const int* __restrict__ pcnt,
                       const float* __restrict__ Wp1, const float* __restrict__ bp1,
                       const float* __restrict__ Wp2, const float* __restrict__ bp2,
                       float* __restrict__ out, int G) {
    __shared__ float gs[4][128];
    int tid = threadIdx.x;
    int li = tid >> 6;
    int lane = tid & 63;
    int gi = blockIdx.x * 4 + li;
    if (gi < G) {
        float c = fmaxf((float)pcnt[gi], 1.0f);
        gs[li][lane] = psum[gi * 64 + lane] / c;
        gs[li][64 + lane] = pmax[gi * 64 + lane];
    }
    __syncthreads();
    if (gi >= G) return;
    float acc = bp1[lane];
    #pragma unroll
    for (int k = 0; k < 128; ++k) acc += gs[li][k] * Wp1[k * 64 + lane];
    acc = fmaxf(acc, 0.f);
    float r = acc * Wp2[lane];
    #pragma unroll
    for (int off = 32; off; off >>= 1) r += __shfl_down(r, off, 64);
    if (lane == 0) out[gi] = r + bp2[0];
}

// ---------------- launch ----------------

extern "C" void kernel_launch(void* const* d_in, const int* in_sizes, int n_in,
                              void* d_out, int out_size, void* d_ws, size_t ws_size,
                              hipStream_t stream) {
    const float* x    = (const float*)d_in[0];
    const int*   esrc = (const int*)d_in[1];
    const int*   edst = (const int*)d_in[2];
    const int*   batch= (const int*)d_in[3];
    const float* W1 = (const float*)d_in[4];  const float* b1 = (const float*)d_in[5];
    const float* W2 = (const float*)d_in[6];  const float* b2 = (const float*)d_in[7];
    const float* W3 = (const float*)d_in[8];  const float* b3 = (const float*)d_in[9];
    const float* Wp1= (const float*)d_in[10]; const float* bp1= (const float*)d_in[11];
    const float* Wp2= (const float*)d_in[12]; const float* bp2= (const float*)d_in[13];
    float* out = (float*)d_out;

    char* ws = (char*)d_ws;
    // zero-init region (contiguous): [cnt][psum][pmax][pcnt]
    int*   cnt     = (int*)  (ws + 0);          // N ints
    float* psum    = (float*)(ws + 400000);     // G*64 floats -> 924288
    float* pmax    = (float*)(ws + 924288);     // G*64 floats -> 1448576
    int*   pcnt    = (int*)  (ws + 1448576);    // G ints -> 1456768
    const size_t ZBYTES = 1456768;
    float* dinv    = (float*)(ws + 1456768);    // N floats -> 1856768
    int*   prp     = (int*)  (ws + 1856768);    // N+1 ints -> 2256896 (pad to 2257408)
    int*   bsum    = (int*)  (ws + 2257408);    // 128 ints -> 2257920
    int*   boff    = (int*)  (ws + 2257920);    // 128 ints -> 2258432
    int*   csr_pad = (int*)  (ws + 2258432);    // CSRCAP ints -> 12658432
    float* p1      = (float*)(ws + 12658432);   // (N+1)*64 floats -> 38258688
    float* p2      = (float*)(ws + 38258688);   // (N+1)*64 floats -> 63858944
    int*   ticket  = (int*)  (ws + 12658432);   // E ints, overlays p1 (dead before layer1)
    float* px      = (float*)(ws + 38258688);   // (N+1)*9 floats, overlays p2 (dead after layer1)

    hipMemsetAsync(ws, 0, ZBYTES, stream);

    k_cnt    <<<(NE + 255) / 256, 256, 0, stream>>>(edst, cnt, ticket, batch, pcnt);
    k_scan1  <<<NBLK, 256, 0, stream>>>(cnt, bsum, x, dinv, px, p1, p2);
    k_scan2  <<<1, 128, 0, stream>>>(bsum, boff, NBLK);
    k_scan3  <<<NBLK, 256, 0, stream>>>(cnt, boff, prp, NN);
    k_padinit<<<(CSRCAP / 4 + 255) / 256, 256, 0, stream>>>(csr_pad);
    k_fill   <<<(NE + 255) / 256, 256, 0, stream>>>(esrc, edst, prp, ticket, csr_pad, NE);

    int nbl = NN / 32;  // 3125, exact
    k_layer<9, 0><<<nbl, 256, 0, stream>>>(px, W1, b1, dinv, csr_pad, prp, batch, p1, psum, pmax);
    k_layer<64, 0><<<nbl, 256, 0, stream>>>(p1, W2, b2, dinv, csr_pad, prp, batch, p2, psum, pmax);
    k_layer<64, 1><<<nbl, 256, 0, stream>>>(p2, W3, b3, dinv, csr_pad, prp, batch, p1, psum, pmax);

    k_pred <<<(NG + 3) / 4, 256, 0, stream>>>(psum, pmax, pcnt, Wp1, bp1, Wp2, bp2, out, NG);
}